// Round 19
// baseline (242.859 us; speedup 1.0000x reference)
//
#include <hip/hip_runtime.h>

// ---------------------------------------------------------------------------
// SAGEConvNet round 18: R14 pipeline, but fusion moved to pass1∥proj1 with
// pass1's LDS cut to ~20KB (CAPL=46, two 2048-edge binning rounds) so the
// fused kernel runs 8 blocks/CU (32 waves) — proj1 at full occupancy.
//   setup -> fused(pass1 ∥ proj1) -> pass2 -> [gather v6 -> proj2]x -> head.
// ---------------------------------------------------------------------------

static inline size_t ws_align(size_t x) { return (x + 511) & ~size_t(511); }

#define MAXBC  104     // max coarse buckets supported (N <= 104*1024)
#define CAPL   46      // LDS slots per bucket per ROUND (avg fill ~21)
#define EB_CAP 24576   // ebuf region capacity per bucket

using frag_ab = __attribute__((ext_vector_type(8))) short;   // 8 bf16
using f32x4   = __attribute__((ext_vector_type(4))) float;   // 4 fp32 acc

__device__ inline short f2bf(float f) {            // RNE fp32 -> bf16
    unsigned u = __builtin_bit_cast(unsigned, f);
    u += 0x7fff + ((u >> 16) & 1);
    return (short)(u >> 16);
}
__device__ inline float b2f(unsigned short h) {
    unsigned u = ((unsigned)h) << 16;
    return __builtin_bit_cast(float, u);
}

// ----------------------------- setup -----------------------------------------
// fw arena (bf16): [0,8192) W1l | [8192,16384) W1r | +4096 each W2l,W2r,W3l,W3r
// | [32768,36864) Wout zero-padded to 64 cols. Block 0 zeroes bcur.
__global__ void setup_kernel(const float* __restrict__ W1l, const float* __restrict__ W1r,
                             const float* __restrict__ W2l, const float* __restrict__ W2r,
                             const float* __restrict__ W3l, const float* __restrict__ W3r,
                             const float* __restrict__ Wout,
                             unsigned short* __restrict__ fw, int* __restrict__ bcur) {
    const int idx = blockIdx.x * 256 + threadIdx.x;   // 0..36863
    if (blockIdx.x == 0 && threadIdx.x < MAXBC) bcur[threadIdx.x] = 0;
    if (idx >= 36864) return;
    if (idx < 32768) {
        const float* W;
        unsigned short* out;
        int F, rel;
        if (idx < 8192)       { W = W1l; out = fw;        F = 128; rel = idx; }
        else if (idx < 16384) { W = W1r; out = fw + 8192; F = 128; rel = idx - 8192; }
        else {
            const int q = (idx - 16384) >> 12;
            rel = (idx - 16384) & 4095;
            F = 64;
            W = (q == 0) ? W2l : (q == 1) ? W2r : (q == 2) ? W3l : W3r;
            out = fw + 16384 + q * 4096;
        }
        const int k = rel % F;                // rel = col*F + k
        const int col = rel / F;
        out[(k >> 3) * 512 + col * 8 + (k & 7)] = (unsigned short)f2bf(W[rel]);
    } else {
        const int rel = idx - 32768;          // [0,4096): col*64 + k
        const int col = rel / 64;
        const int k = rel % 64;
        const float v = (col < 40) ? Wout[col * 64 + k] : 0.0f;
        fw[32768 + (k >> 3) * 512 + col * 8 + (k & 7)] = (unsigned short)f2bf(v);
    }
}

// ----------------------------- pass1 body (low-LDS, 2 rounds) ----------------
__device__ __forceinline__ void pass1_body(const int* __restrict__ src, const int* __restrict__ dst,
                                           int* __restrict__ bcur, unsigned* __restrict__ ebuf,
                                           int nE, int nN, int nbc, int bid) {
    __shared__ unsigned lbuf[MAXBC][CAPL];
    __shared__ int bcnt[MAXBC];
    __shared__ int gbase[MAXBC];
    const int t = threadIdx.x;
    const int wid = t >> 6, lane = t & 63;

#pragma unroll
    for (int round = 0; round < 2; ++round) {
        const int e0 = bid * 4096 + round * 2048;
        for (int i = t; i < MAXBC; i += 256) bcnt[i] = 0;
        __syncthreads();
#pragma unroll
        for (int q = 0; q < 8; ++q) {
            const int e = e0 + q * 256 + t;
            if (e < nE) {
                const unsigned d = (unsigned)dst[e];
                const unsigned s = (unsigned)src[e];
                if (d < (unsigned)nN && s < (unsigned)nN) {
                    const int cb = (int)(d >> 10);
                    const unsigned v = ((d & 1023u) << 17) | s;
                    const int pos = atomicAdd(&bcnt[cb], 1);
                    if (pos < CAPL) {
                        lbuf[cb][pos] = v;
                    } else {
                        // very rare overflow: direct global append (contained)
                        const int gp = atomicAdd(&bcur[cb], 1);
                        if (gp < EB_CAP) ebuf[(size_t)cb * EB_CAP + gp] = v;
                    }
                }
            }
        }
        __syncthreads();
        for (int b = t; b < nbc; b += 256) {
            const int cnt = min(bcnt[b], CAPL);
            bcnt[b] = cnt;
            gbase[b] = (cnt > 0) ? atomicAdd(&bcur[b], cnt) : 0;
        }
        __syncthreads();
        for (int b = wid; b < nbc; b += 4) {
            const int cnt = bcnt[b];
            const int gb = gbase[b];
            for (int i = lane; i < cnt; i += 64) {
                const int gp = gb + i;
                if (gp < EB_CAP) ebuf[(size_t)b * EB_CAP + gp] = lbuf[b][i];
            }
        }
        __syncthreads();
    }
}

// ----------------------------- proj body -------------------------------------
// 16 rows/wave dual-output MFMA projection; xl, xr stored bf16.
template<int F, bool AF32>
__device__ __forceinline__ void proj_body(const void* __restrict__ Aptr,
                                          const unsigned short* __restrict__ fwl,
                                          const unsigned short* __restrict__ fwr,
                                          const float* __restrict__ bias,
                                          unsigned short* __restrict__ xl,
                                          unsigned short* __restrict__ xr,
                                          int nN, int bid) {
    const int t    = threadIdx.x;
    const int wave = t >> 6;
    const int lane = t & 63;
    const int lg   = lane >> 4;
    const int lr   = lane & 15;
    const int row0 = bid * 64 + wave * 16;

    const float*          Af = (const float*)Aptr;
    const unsigned short* Ab = (const unsigned short*)Aptr;

    f32x4 accl[4] = {};
    f32x4 accr[4] = {};

#pragma unroll
    for (int ks = 0; ks < F / 32; ++ks) {
        const int k0 = ks * 32 + lg * 8;
        frag_ab afr;
        {
            int row = row0 + lr;
            if (row >= nN) row = nN - 1;
            if constexpr (AF32) {
                const float4 f0 = *reinterpret_cast<const float4*>(Af + (size_t)row * F + k0);
                const float4 f1 = *reinterpret_cast<const float4*>(Af + (size_t)row * F + k0 + 4);
                afr[0] = f2bf(f0.x); afr[1] = f2bf(f0.y); afr[2] = f2bf(f0.z); afr[3] = f2bf(f0.w);
                afr[4] = f2bf(f1.x); afr[5] = f2bf(f1.y); afr[6] = f2bf(f1.z); afr[7] = f2bf(f1.w);
            } else {
                afr = *reinterpret_cast<const frag_ab*>(Ab + (size_t)row * F + k0);
            }
        }
        const int ob = (ks * 4 + lg) * 512;
#pragma unroll
        for (int nf = 0; nf < 4; ++nf) {
            const int col = nf * 16 + lr;
            const frag_ab bl = *reinterpret_cast<const frag_ab*>(fwl + ob + col * 8);
            const frag_ab br = *reinterpret_cast<const frag_ab*>(fwr + ob + col * 8);
            accl[nf] = __builtin_amdgcn_mfma_f32_16x16x32_bf16(afr, bl, accl[nf], 0, 0, 0);
            accr[nf] = __builtin_amdgcn_mfma_f32_16x16x32_bf16(afr, br, accr[nf], 0, 0, 0);
        }
    }

    // C/D layout: col=lane&15, row=(lane>>4)*4+reg   [m89-verified]
#pragma unroll
    for (int nf = 0; nf < 4; ++nf) {
        const int col = nf * 16 + lr;
        const float bv = bias[col];
#pragma unroll
        for (int j = 0; j < 4; ++j) {
            const int row = row0 + lg * 4 + j;
            if (row < nN) {
                xl[(size_t)row * 64 + col] = (unsigned short)f2bf(accl[nf][j]);
                xr[(size_t)row * 64 + col] = (unsigned short)f2bf(accr[nf][j] + bv);
            }
        }
    }
}

// ----------------------------- fused pass1 ∥ proj1 ---------------------------
__global__ void fused_p1_proj1(const int* __restrict__ src, const int* __restrict__ dst,
                               int* __restrict__ bcur, unsigned* __restrict__ ebuf,
                               int nE, int nN, int nbc, int nbP1,
                               const float* __restrict__ x,
                               const unsigned short* __restrict__ fwl,
                               const unsigned short* __restrict__ fwr,
                               const float* __restrict__ bias,
                               unsigned short* __restrict__ xl,
                               unsigned short* __restrict__ xr) {
    if ((int)blockIdx.x < nbP1)
        pass1_body(src, dst, bcur, ebuf, nE, nN, nbc, blockIdx.x);
    else
        proj_body<128, true>(x, fwl, fwr, bias, xl, xr, nN, blockIdx.x - nbP1);
}

// standalone proj kernel (layers 2, 3)
template<int F, bool AF32>
__global__ void proj2_mfma(const void* __restrict__ Aptr,
                           const unsigned short* __restrict__ fwl,
                           const unsigned short* __restrict__ fwr,
                           const float* __restrict__ bias,
                           unsigned short* __restrict__ xl,
                           unsigned short* __restrict__ xr,
                           int nN) {
    proj_body<F, AF32>(Aptr, fwl, fwr, bias, xl, xr, nN, blockIdx.x);
}

// ----------------------------- pass2 (standalone, self-scan) -----------------
__global__ void pass2_build(const unsigned* __restrict__ ebuf,
                            const int* __restrict__ bcur,
                            int* __restrict__ rowptr, int* __restrict__ csr,
                            int nN, int nbc) {
    __shared__ int sc[128];
    __shared__ int lcnt[1024];
    __shared__ int lcur[1024];
    __shared__ int sdata[256];
    const int b = blockIdx.x;
    const int node0 = b << 10;
    const int nloc = min(1024, nN - node0);
    if (nloc <= 0) return;
    const int t = threadIdx.x;

    // self-scan of clamped bucket counts (nbc <= 104 < 128)
    if (t < 128) sc[t] = (t < nbc) ? min(bcur[t], EB_CAP) : 0;
    __syncthreads();
    for (int off = 1; off < 128; off <<= 1) {
        int add = (t < 128 && t >= off) ? sc[t - off] : 0;
        __syncthreads();
        if (t < 128) sc[t] += add;
        __syncthreads();
    }
    const int cnt  = min(bcur[b], EB_CAP);
    const int base = sc[b] - cnt;     // exclusive prefix
    const unsigned* eb = ebuf + (size_t)b * EB_CAP;

    for (int i = t; i < 1024; i += 256) lcnt[i] = 0;
    __syncthreads();
    for (int i = t; i < cnt; i += 256) atomicAdd(&lcnt[eb[i] >> 17], 1);
    __syncthreads();
    int v[4];
    int tsum = 0;
#pragma unroll
    for (int q = 0; q < 4; ++q) { v[q] = lcnt[t * 4 + q]; tsum += v[q]; }
    sdata[t] = tsum;
    __syncthreads();
    for (int off = 1; off < 256; off <<= 1) {
        int add = (t >= off) ? sdata[t - off] : 0;
        __syncthreads();
        sdata[t] += add;
        __syncthreads();
    }
    int run = sdata[t] - tsum;
#pragma unroll
    for (int q = 0; q < 4; ++q) {
        const int l = t * 4 + q;
        lcur[l] = run;
        if (l < nloc) rowptr[node0 + l] = base + run;
        run += v[q];
    }
    if (b == nbc - 1 && t == 0) rowptr[nN] = base + cnt;
    __syncthreads();
    for (int i = t; i < cnt; i += 256) {
        const unsigned ev = eb[i];
        const int pos = atomicAdd(&lcur[ev >> 17], 1);
        csr[base + pos] = (int)((ev & 0x1FFFFu) << 7);   // byte offset into xl
    }
}

// ----------------------------- gather-mean v6 --------------------------------
template<bool DOELU>
__global__ void gather_kernel(const unsigned short* __restrict__ xl,
                              const unsigned short* __restrict__ xr,
                              const int* __restrict__ rowptr, const int* __restrict__ csr,
                              unsigned short* __restrict__ outp, int nN, int nE) {
    const int node = blockIdx.x * (blockDim.x >> 6) + (threadIdx.x >> 6);
    if (node >= nN) return;
    const int lane = threadIdx.x & 63;
    int b = rowptr[node];
    int e = rowptr[node + 1];
    b = max(0, min(b, nE));
    e = max(b, min(e, nE));
    b = __builtin_amdgcn_readfirstlane(b);
    e = __builtin_amdgcn_readfirstlane(e);
    const float d = (float)(e - b);
    const char* xlb = (const char*)xl + (lane << 1);

    float acc = 0.f;
    int i = b;
    for (; i + 16 <= e; i += 16) {
        unsigned short v[16];
#pragma unroll
        for (int j = 0; j < 16; ++j) {
            const unsigned s = (unsigned)csr[i + j];       // s_load (uniform)
            v[j] = *(const unsigned short*)(xlb + s);
        }
#pragma unroll
        for (int j = 0; j < 16; ++j) acc += b2f(v[j]);
    }
    if (i < e) {
        const int lim = e - i;       // 1..15
        unsigned short v[16];
#pragma unroll
        for (int j = 0; j < 16; ++j) {
            const unsigned s = (unsigned)csr[i + min(j, lim - 1)];
            v[j] = *(const unsigned short*)(xlb + s);
        }
#pragma unroll
        for (int j = 0; j < 16; ++j) acc += (j < lim) ? b2f(v[j]) : 0.f;
    }

    float vout = acc / fmaxf(d, 1.0f) + b2f(xr[(size_t)node * 64 + lane]);
    if (DOELU) vout = vout > 0.f ? vout : expm1f(vout);
    outp[(size_t)node * 64 + lane] = (unsigned short)f2bf(vout);
}

// ----------------------------- head (MFMA, 40 cols) --------------------------
__global__ void head_mfma(const unsigned short* __restrict__ A,   // bf16 [N][64]
                          const unsigned short* __restrict__ fwo, // prepped Wout
                          const float* __restrict__ bias,         // 40
                          float* __restrict__ out, int nN) {
    const int t    = threadIdx.x;
    const int wave = t >> 6;
    const int lane = t & 63;
    const int lg   = lane >> 4;
    const int lr   = lane & 15;
    const int row0 = blockIdx.x * 64 + wave * 16;

    f32x4 acc[3] = {};

#pragma unroll
    for (int ks = 0; ks < 2; ++ks) {
        const int k0 = ks * 32 + lg * 8;
        frag_ab afr;
        {
            int row = row0 + lr;
            if (row >= nN) row = nN - 1;
            afr = *reinterpret_cast<const frag_ab*>(A + (size_t)row * 64 + k0);
        }
        const int ob = (ks * 4 + lg) * 512;
#pragma unroll
        for (int nf = 0; nf < 3; ++nf) {
            const int col = nf * 16 + lr;
            const frag_ab bo = *reinterpret_cast<const frag_ab*>(fwo + ob + col * 8);
            acc[nf] = __builtin_amdgcn_mfma_f32_16x16x32_bf16(afr, bo, acc[nf], 0, 0, 0);
        }
    }

#pragma unroll
    for (int nf = 0; nf < 3; ++nf) {
        const int col = nf * 16 + lr;
        if (col >= 40) continue;
        const float bv = bias[col];
#pragma unroll
        for (int j = 0; j < 4; ++j) {
            const int row = row0 + lg * 4 + j;
            if (row < nN)
                out[(size_t)row * 40 + col] = acc[nf][j] + bv;
        }
    }
}

// ----------------------------- launch ---------------------------------------

extern "C" void kernel_launch(void* const* d_in, const int* in_sizes, int n_in,
                              void* d_out, int out_size, void* d_ws, size_t ws_size,
                              hipStream_t stream) {
    const float* x    = (const float*)d_in[0];
    const int*   ei   = (const int*)d_in[1];
    const float* W1l  = (const float*)d_in[2];
    const float* b1   = (const float*)d_in[3];
    const float* W1r  = (const float*)d_in[4];
    const float* W2l  = (const float*)d_in[5];
    const float* b2   = (const float*)d_in[6];
    const float* W2r  = (const float*)d_in[7];
    const float* W3l  = (const float*)d_in[8];
    const float* b3   = (const float*)d_in[9];
    const float* W3r  = (const float*)d_in[10];
    const float* Wout = (const float*)d_in[11];
    const float* bout = (const float*)d_in[12];

    const int N = in_sizes[0] / 128;   // 100000
    const int E = in_sizes[1] / 2;     // 1600000
    const int* src  = ei;
    const int* dstA = ei + E;
    const int nbc = (N + 1023) >> 10;
    const int nbP1 = (E + 4095) / 4096;

    char* ws = (char*)d_ws;
    size_t o = 0;
    int* bcur    = (int*)(ws + o); o += ws_align((size_t)MAXBC * 4);
    int* rowptr  = (int*)(ws + o); o += ws_align((size_t)(N + 1) * 4);
    int* csr     = (int*)(ws + o); o += ws_align((size_t)E * 4);
    unsigned* ebuf = (unsigned*)(ws + o); o += ws_align((size_t)MAXBC * EB_CAP * 4);
    unsigned short* fw  = (unsigned short*)(ws + o); o += ws_align((size_t)36864 * 2);
    unsigned short* xl  = (unsigned short*)(ws + o); o += ws_align((size_t)N * 64 * 2);
    unsigned short* xr  = (unsigned short*)(ws + o); o += ws_align((size_t)N * 64 * 2);
    unsigned short* hAb = (unsigned short*)(ws + o); o += ws_align((size_t)N * 64 * 2);
    unsigned short* hBb = (unsigned short*)(ws + o); o += ws_align((size_t)N * 64 * 2);
    unsigned short* h3b = (unsigned short*)(ws + o); o += ws_align((size_t)N * 64 * 2);
    float* outp = (float*)d_out;

    const int projGrid = (N + 63) / 64;
    const int gatherGrid = (N + 3) / 4;

    const unsigned short* fw1l = fw;
    const unsigned short* fw1r = fw + 8192;
    const unsigned short* fw2l = fw + 16384;
    const unsigned short* fw2r = fw + 16384 + 4096;
    const unsigned short* fw3l = fw + 16384 + 8192;
    const unsigned short* fw3r = fw + 16384 + 12288;
    const unsigned short* fwo  = fw + 32768;

    // ---- setup: weight prep + bcur zero ----
    setup_kernel<<<144, 256, 0, stream>>>(W1l, W1r, W2l, W2r, W3l, W3r, Wout, fw, bcur);

    // ---- pass1 ∥ proj1 (low-LDS co-schedule: 8 blocks/CU) ----
    fused_p1_proj1<<<nbP1 + projGrid, 256, 0, stream>>>(
        src, dstA, bcur, ebuf, E, N, nbc, nbP1,
        x, fw1l, fw1r, b1, xl, xr);

    // ---- CSR finalize ----
    pass2_build<<<nbc, 256, 0, stream>>>(ebuf, bcur, rowptr, csr, N, nbc);

    // ---- layer 1 gather (ELU) ----
    gather_kernel<true><<<gatherGrid, 256, 0, stream>>>(xl, xr, rowptr, csr, hAb, N, E);

    // ---- layer 2 ----
    proj2_mfma<64, false><<<projGrid, 256, 0, stream>>>(hAb, fw2l, fw2r, b2, xl, xr, N);
    gather_kernel<true><<<gatherGrid, 256, 0, stream>>>(xl, xr, rowptr, csr, hBb, N, E);

    // ---- layer 3 ----
    proj2_mfma<64, false><<<projGrid, 256, 0, stream>>>(hBb, fw3l, fw3r, b3, xl, xr, N);
    gather_kernel<false><<<gatherGrid, 256, 0, stream>>>(xl, xr, rowptr, csr, h3b, N, E);

    // ---- head (MFMA, 40 cols) ----
    head_mfma<<<projGrid, 256, 0, stream>>>(h3b, fwo, bout, outp, N);
}

// Round 20
// 239.285 us; speedup vs baseline: 1.0149x; 1.0149x over previous
//
#include <hip/hip_runtime.h>

// ---------------------------------------------------------------------------
// SAGEConvNet round 19: restore best configuration (R14/R17, 239.4µs x2).
//   setup_kernel -> pass1_bin -> fused(pass2 ∥ proj1) -> [gather v6 -> proj2]x
//   -> head_mfma.
// Gathers pinned at compulsory per-XCD L2-fill rate (43.4µs each; FETCH=90MB
// = 8 XCDs x ~86% of 12.8MB xl). Build+proj schedule is the measured optimum
// of five variants.
// ---------------------------------------------------------------------------

static inline size_t ws_align(size_t x) { return (x + 511) & ~size_t(511); }

#define MAXBC  104     // max coarse buckets supported (N <= 104*1024)
#define CAPL   96      // LDS slots per bucket per block (avg fill ~42)
#define EB_CAP 24576   // ebuf region capacity per bucket

using frag_ab = __attribute__((ext_vector_type(8))) short;   // 8 bf16
using f32x4   = __attribute__((ext_vector_type(4))) float;   // 4 fp32 acc

__device__ inline short f2bf(float f) {            // RNE fp32 -> bf16
    unsigned u = __builtin_bit_cast(unsigned, f);
    u += 0x7fff + ((u >> 16) & 1);
    return (short)(u >> 16);
}
__device__ inline float b2f(unsigned short h) {
    unsigned u = ((unsigned)h) << 16;
    return __builtin_bit_cast(float, u);
}

// ----------------------------- setup -----------------------------------------
// fw arena (bf16): [0,8192) W1l | [8192,16384) W1r | +4096 each W2l,W2r,W3l,W3r
// | [32768,36864) Wout zero-padded to 64 cols. Block 0 zeroes bcur.
__global__ void setup_kernel(const float* __restrict__ W1l, const float* __restrict__ W1r,
                             const float* __restrict__ W2l, const float* __restrict__ W2r,
                             const float* __restrict__ W3l, const float* __restrict__ W3r,
                             const float* __restrict__ Wout,
                             unsigned short* __restrict__ fw, int* __restrict__ bcur) {
    const int idx = blockIdx.x * 256 + threadIdx.x;   // 0..36863
    if (blockIdx.x == 0 && threadIdx.x < MAXBC) bcur[threadIdx.x] = 0;
    if (idx >= 36864) return;
    if (idx < 32768) {
        const float* W;
        unsigned short* out;
        int F, rel;
        if (idx < 8192)       { W = W1l; out = fw;        F = 128; rel = idx; }
        else if (idx < 16384) { W = W1r; out = fw + 8192; F = 128; rel = idx - 8192; }
        else {
            const int q = (idx - 16384) >> 12;
            rel = (idx - 16384) & 4095;
            F = 64;
            W = (q == 0) ? W2l : (q == 1) ? W2r : (q == 2) ? W3l : W3r;
            out = fw + 16384 + q * 4096;
        }
        const int k = rel % F;                // rel = col*F + k
        const int col = rel / F;
        out[(k >> 3) * 512 + col * 8 + (k & 7)] = (unsigned short)f2bf(W[rel]);
    } else {
        const int rel = idx - 32768;          // [0,4096): col*64 + k
        const int col = rel / 64;
        const int k = rel % 64;
        const float v = (col < 40) ? Wout[col * 64 + k] : 0.0f;
        fw[32768 + (k >> 3) * 512 + col * 8 + (k & 7)] = (unsigned short)f2bf(v);
    }
}

// ----------------------------- pass1 (standalone) ----------------------------
__global__ void pass1_bin(const int* __restrict__ src, const int* __restrict__ dst,
                          int* __restrict__ bcur, unsigned* __restrict__ ebuf,
                          int nE, int nN, int nbc) {
    __shared__ unsigned lbuf[MAXBC][CAPL];
    __shared__ int bcnt[MAXBC];
    __shared__ int gbase[MAXBC];
    const int t = threadIdx.x;
    const int e0 = blockIdx.x * 4096;
    for (int i = t; i < MAXBC; i += 256) bcnt[i] = 0;
    __syncthreads();
#pragma unroll
    for (int q = 0; q < 16; ++q) {
        const int e = e0 + q * 256 + t;
        if (e < nE) {
            const unsigned d = (unsigned)dst[e];
            const unsigned s = (unsigned)src[e];
            if (d < (unsigned)nN && s < (unsigned)nN) {
                const int cb = (int)(d >> 10);
                const unsigned v = ((d & 1023u) << 17) | s;
                const int pos = atomicAdd(&bcnt[cb], 1);
                if (pos < CAPL) {
                    lbuf[cb][pos] = v;
                } else {
                    const int gp = atomicAdd(&bcur[cb], 1);
                    if (gp < EB_CAP) ebuf[(size_t)cb * EB_CAP + gp] = v;
                }
            }
        }
    }
    __syncthreads();
    for (int b = t; b < nbc; b += 256) {
        const int cnt = min(bcnt[b], CAPL);
        bcnt[b] = cnt;
        gbase[b] = (cnt > 0) ? atomicAdd(&bcur[b], cnt) : 0;
    }
    __syncthreads();
    const int wid = t >> 6, lane = t & 63;
    for (int b = wid; b < nbc; b += 4) {
        const int cnt = bcnt[b];
        const int gb = gbase[b];
        for (int i = lane; i < cnt; i += 64) {
            const int gp = gb + i;
            if (gp < EB_CAP) ebuf[(size_t)b * EB_CAP + gp] = lbuf[b][i];
        }
    }
}

// ----------------------------- pass2 body (self-scan) ------------------------
__device__ __forceinline__ void pass2_body(const unsigned* __restrict__ ebuf,
                                           const int* __restrict__ bcur,
                                           int* __restrict__ rowptr, int* __restrict__ csr,
                                           int nN, int nbc, int b) {
    __shared__ int sc[128];
    __shared__ int lcnt[1024];
    __shared__ int lcur[1024];
    __shared__ int sdata[256];
    const int node0 = b << 10;
    const int nloc = min(1024, nN - node0);
    if (nloc <= 0) return;
    const int t = threadIdx.x;

    // self-scan of clamped bucket counts (nbc <= 104 < 128)
    if (t < 128) sc[t] = (t < nbc) ? min(bcur[t], EB_CAP) : 0;
    __syncthreads();
    for (int off = 1; off < 128; off <<= 1) {
        int add = (t < 128 && t >= off) ? sc[t - off] : 0;
        __syncthreads();
        if (t < 128) sc[t] += add;
        __syncthreads();
    }
    const int cnt  = min(bcur[b], EB_CAP);
    const int base = sc[b] - cnt;     // exclusive prefix
    const unsigned* eb = ebuf + (size_t)b * EB_CAP;

    for (int i = t; i < 1024; i += 256) lcnt[i] = 0;
    __syncthreads();
    for (int i = t; i < cnt; i += 256) atomicAdd(&lcnt[eb[i] >> 17], 1);
    __syncthreads();
    int v[4];
    int tsum = 0;
#pragma unroll
    for (int q = 0; q < 4; ++q) { v[q] = lcnt[t * 4 + q]; tsum += v[q]; }
    sdata[t] = tsum;
    __syncthreads();
    for (int off = 1; off < 256; off <<= 1) {
        int add = (t >= off) ? sdata[t - off] : 0;
        __syncthreads();
        sdata[t] += add;
        __syncthreads();
    }
    int run = sdata[t] - tsum;
#pragma unroll
    for (int q = 0; q < 4; ++q) {
        const int l = t * 4 + q;
        lcur[l] = run;
        if (l < nloc) rowptr[node0 + l] = base + run;
        run += v[q];
    }
    if (b == nbc - 1 && t == 0) rowptr[nN] = base + cnt;
    __syncthreads();
    for (int i = t; i < cnt; i += 256) {
        const unsigned ev = eb[i];
        const int pos = atomicAdd(&lcur[ev >> 17], 1);
        csr[base + pos] = (int)((ev & 0x1FFFFu) << 7);   // byte offset into xl
    }
}

// ----------------------------- proj body -------------------------------------
// 16 rows/wave dual-output MFMA projection; xl, xr stored bf16.
template<int F, bool AF32>
__device__ __forceinline__ void proj_body(const void* __restrict__ Aptr,
                                          const unsigned short* __restrict__ fwl,
                                          const unsigned short* __restrict__ fwr,
                                          const float* __restrict__ bias,
                                          unsigned short* __restrict__ xl,
                                          unsigned short* __restrict__ xr,
                                          int nN, int bid) {
    const int t    = threadIdx.x;
    const int wave = t >> 6;
    const int lane = t & 63;
    const int lg   = lane >> 4;
    const int lr   = lane & 15;
    const int row0 = bid * 64 + wave * 16;

    const float*          Af = (const float*)Aptr;
    const unsigned short* Ab = (const unsigned short*)Aptr;

    f32x4 accl[4] = {};
    f32x4 accr[4] = {};

#pragma unroll
    for (int ks = 0; ks < F / 32; ++ks) {
        const int k0 = ks * 32 + lg * 8;
        frag_ab afr;
        {
            int row = row0 + lr;
            if (row >= nN) row = nN - 1;
            if constexpr (AF32) {
                const float4 f0 = *reinterpret_cast<const float4*>(Af + (size_t)row * F + k0);
                const float4 f1 = *reinterpret_cast<const float4*>(Af + (size_t)row * F + k0 + 4);
                afr[0] = f2bf(f0.x); afr[1] = f2bf(f0.y); afr[2] = f2bf(f0.z); afr[3] = f2bf(f0.w);
                afr[4] = f2bf(f1.x); afr[5] = f2bf(f1.y); afr[6] = f2bf(f1.z); afr[7] = f2bf(f1.w);
            } else {
                afr = *reinterpret_cast<const frag_ab*>(Ab + (size_t)row * F + k0);
            }
        }
        const int ob = (ks * 4 + lg) * 512;
#pragma unroll
        for (int nf = 0; nf < 4; ++nf) {
            const int col = nf * 16 + lr;
            const frag_ab bl = *reinterpret_cast<const frag_ab*>(fwl + ob + col * 8);
            const frag_ab br = *reinterpret_cast<const frag_ab*>(fwr + ob + col * 8);
            accl[nf] = __builtin_amdgcn_mfma_f32_16x16x32_bf16(afr, bl, accl[nf], 0, 0, 0);
            accr[nf] = __builtin_amdgcn_mfma_f32_16x16x32_bf16(afr, br, accr[nf], 0, 0, 0);
        }
    }

    // C/D layout: col=lane&15, row=(lane>>4)*4+reg   [m89-verified]
#pragma unroll
    for (int nf = 0; nf < 4; ++nf) {
        const int col = nf * 16 + lr;
        const float bv = bias[col];
#pragma unroll
        for (int j = 0; j < 4; ++j) {
            const int row = row0 + lg * 4 + j;
            if (row < nN) {
                xl[(size_t)row * 64 + col] = (unsigned short)f2bf(accl[nf][j]);
                xr[(size_t)row * 64 + col] = (unsigned short)f2bf(accr[nf][j] + bv);
            }
        }
    }
}

// ----------------------------- fused pass2 ∥ proj1 ---------------------------
__global__ void fused_p2_proj1(const unsigned* __restrict__ ebuf,
                               const int* __restrict__ bcur,
                               int* __restrict__ rowptr, int* __restrict__ csr,
                               int nN, int nbc,
                               const float* __restrict__ x,
                               const unsigned short* __restrict__ fwl,
                               const unsigned short* __restrict__ fwr,
                               const float* __restrict__ bias,
                               unsigned short* __restrict__ xl,
                               unsigned short* __restrict__ xr) {
    if ((int)blockIdx.x < nbc)
        pass2_body(ebuf, bcur, rowptr, csr, nN, nbc, blockIdx.x);
    else
        proj_body<128, true>(x, fwl, fwr, bias, xl, xr, nN, blockIdx.x - nbc);
}

// standalone proj kernel (layers 2, 3)
template<int F, bool AF32>
__global__ void proj2_mfma(const void* __restrict__ Aptr,
                           const unsigned short* __restrict__ fwl,
                           const unsigned short* __restrict__ fwr,
                           const float* __restrict__ bias,
                           unsigned short* __restrict__ xl,
                           unsigned short* __restrict__ xr,
                           int nN) {
    proj_body<F, AF32>(Aptr, fwl, fwr, bias, xl, xr, nN, blockIdx.x);
}

// ----------------------------- gather-mean v6 --------------------------------
template<bool DOELU>
__global__ void gather_kernel(const unsigned short* __restrict__ xl,
                              const unsigned short* __restrict__ xr,
                              const int* __restrict__ rowptr, const int* __restrict__ csr,
                              unsigned short* __restrict__ outp, int nN, int nE) {
    const int node = blockIdx.x * (blockDim.x >> 6) + (threadIdx.x >> 6);
    if (node >= nN) return;
    const int lane = threadIdx.x & 63;
    int b = rowptr[node];
    int e = rowptr[node + 1];
    b = max(0, min(b, nE));
    e = max(b, min(e, nE));
    b = __builtin_amdgcn_readfirstlane(b);
    e = __builtin_amdgcn_readfirstlane(e);
    const float d = (float)(e - b);
    const char* xlb = (const char*)xl + (lane << 1);

    float acc = 0.f;
    int i = b;
    for (; i + 16 <= e; i += 16) {
        unsigned short v[16];
#pragma unroll
        for (int j = 0; j < 16; ++j) {
            const unsigned s = (unsigned)csr[i + j];       // s_load (uniform)
            v[j] = *(const unsigned short*)(xlb + s);
        }
#pragma unroll
        for (int j = 0; j < 16; ++j) acc += b2f(v[j]);
    }
    if (i < e) {
        const int lim = e - i;       // 1..15
        unsigned short v[16];
#pragma unroll
        for (int j = 0; j < 16; ++j) {
            const unsigned s = (unsigned)csr[i + min(j, lim - 1)];
            v[j] = *(const unsigned short*)(xlb + s);
        }
#pragma unroll
        for (int j = 0; j < 16; ++j) acc += (j < lim) ? b2f(v[j]) : 0.f;
    }

    float vout = acc / fmaxf(d, 1.0f) + b2f(xr[(size_t)node * 64 + lane]);
    if (DOELU) vout = vout > 0.f ? vout : expm1f(vout);
    outp[(size_t)node * 64 + lane] = (unsigned short)f2bf(vout);
}

// ----------------------------- head (MFMA, 40 cols) --------------------------
__global__ void head_mfma(const unsigned short* __restrict__ A,   // bf16 [N][64]
                          const unsigned short* __restrict__ fwo, // prepped Wout
                          const float* __restrict__ bias,         // 40
                          float* __restrict__ out, int nN) {
    const int t    = threadIdx.x;
    const int wave = t >> 6;
    const int lane = t & 63;
    const int lg   = lane >> 4;
    const int lr   = lane & 15;
    const int row0 = blockIdx.x * 64 + wave * 16;

    f32x4 acc[3] = {};

#pragma unroll
    for (int ks = 0; ks < 2; ++ks) {
        const int k0 = ks * 32 + lg * 8;
        frag_ab afr;
        {
            int row = row0 + lr;
            if (row >= nN) row = nN - 1;
            afr = *reinterpret_cast<const frag_ab*>(A + (size_t)row * 64 + k0);
        }
        const int ob = (ks * 4 + lg) * 512;
#pragma unroll
        for (int nf = 0; nf < 3; ++nf) {
            const int col = nf * 16 + lr;
            const frag_ab bo = *reinterpret_cast<const frag_ab*>(fwo + ob + col * 8);
            acc[nf] = __builtin_amdgcn_mfma_f32_16x16x32_bf16(afr, bo, acc[nf], 0, 0, 0);
        }
    }

#pragma unroll
    for (int nf = 0; nf < 3; ++nf) {
        const int col = nf * 16 + lr;
        if (col >= 40) continue;
        const float bv = bias[col];
#pragma unroll
        for (int j = 0; j < 4; ++j) {
            const int row = row0 + lg * 4 + j;
            if (row < nN)
                out[(size_t)row * 40 + col] = acc[nf][j] + bv;
        }
    }
}

// ----------------------------- launch ---------------------------------------

extern "C" void kernel_launch(void* const* d_in, const int* in_sizes, int n_in,
                              void* d_out, int out_size, void* d_ws, size_t ws_size,
                              hipStream_t stream) {
    const float* x    = (const float*)d_in[0];
    const int*   ei   = (const int*)d_in[1];
    const float* W1l  = (const float*)d_in[2];
    const float* b1   = (const float*)d_in[3];
    const float* W1r  = (const float*)d_in[4];
    const float* W2l  = (const float*)d_in[5];
    const float* b2   = (const float*)d_in[6];
    const float* W2r  = (const float*)d_in[7];
    const float* W3l  = (const float*)d_in[8];
    const float* b3   = (const float*)d_in[9];
    const float* W3r  = (const float*)d_in[10];
    const float* Wout = (const float*)d_in[11];
    const float* bout = (const float*)d_in[12];

    const int N = in_sizes[0] / 128;   // 100000
    const int E = in_sizes[1] / 2;     // 1600000
    const int* src  = ei;
    const int* dstA = ei + E;
    const int nbc = (N + 1023) >> 10;
    const int nbP1 = (E + 4095) / 4096;

    char* ws = (char*)d_ws;
    size_t o = 0;
    int* bcur    = (int*)(ws + o); o += ws_align((size_t)MAXBC * 4);
    int* rowptr  = (int*)(ws + o); o += ws_align((size_t)(N + 1) * 4);
    int* csr     = (int*)(ws + o); o += ws_align((size_t)E * 4);
    unsigned* ebuf = (unsigned*)(ws + o); o += ws_align((size_t)MAXBC * EB_CAP * 4);
    unsigned short* fw  = (unsigned short*)(ws + o); o += ws_align((size_t)36864 * 2);
    unsigned short* xl  = (unsigned short*)(ws + o); o += ws_align((size_t)N * 64 * 2);
    unsigned short* xr  = (unsigned short*)(ws + o); o += ws_align((size_t)N * 64 * 2);
    unsigned short* hAb = (unsigned short*)(ws + o); o += ws_align((size_t)N * 64 * 2);
    unsigned short* hBb = (unsigned short*)(ws + o); o += ws_align((size_t)N * 64 * 2);
    unsigned short* h3b = (unsigned short*)(ws + o); o += ws_align((size_t)N * 64 * 2);
    float* outp = (float*)d_out;

    const int projGrid = (N + 63) / 64;
    const int gatherGrid = (N + 3) / 4;

    const unsigned short* fw1l = fw;
    const unsigned short* fw1r = fw + 8192;
    const unsigned short* fw2l = fw + 16384;
    const unsigned short* fw2r = fw + 16384 + 4096;
    const unsigned short* fw3l = fw + 16384 + 8192;
    const unsigned short* fw3r = fw + 16384 + 12288;
    const unsigned short* fwo  = fw + 32768;

    // ---- setup: weight prep + bcur zero ----
    setup_kernel<<<144, 256, 0, stream>>>(W1l, W1r, W2l, W2r, W3l, W3r, Wout, fw, bcur);

    // ---- pass1 (standalone 40KB binning) ----
    pass1_bin<<<nbP1, 256, 0, stream>>>(src, dstA, bcur, ebuf, E, N, nbc);

    // ---- pass2 ∥ proj1 (independent; low-LDS co-schedule) ----
    fused_p2_proj1<<<nbc + projGrid, 256, 0, stream>>>(
        ebuf, bcur, rowptr, csr, N, nbc,
        x, fw1l, fw1r, b1, xl, xr);

    // ---- layer 1 gather (ELU) ----
    gather_kernel<true><<<gatherGrid, 256, 0, stream>>>(xl, xr, rowptr, csr, hAb, N, E);

    // ---- layer 2 ----
    proj2_mfma<64, false><<<projGrid, 256, 0, stream>>>(hAb, fw2l, fw2r, b2, xl, xr, N);
    gather_kernel<true><<<gatherGrid, 256, 0, stream>>>(xl, xr, rowptr, csr, hBb, N, E);

    // ---- layer 3 ----
    proj2_mfma<64, false><<<projGrid, 256, 0, stream>>>(hBb, fw3l, fw3r, b3, xl, xr, N);
    gather_kernel<false><<<gatherGrid, 256, 0, stream>>>(xl, xr, rowptr, csr, h3b, N, E);

    // ---- head (MFMA, 40 cols) ----
    head_mfma<<<projGrid, 256, 0, stream>>>(h3b, fwo, bout, outp, N);
}